// Round 11
// baseline (277.121 us; speedup 1.0000x reference)
//
#include <hip/hip_runtime.h>

typedef _Float16 f16;
typedef f16 f16x8 __attribute__((ext_vector_type(8)));
typedef float f32x4 __attribute__((ext_vector_type(4)));
typedef float f32x16 __attribute__((ext_vector_type(16)));

#define BATCH   32768
#define NF      162
#define ACCH    1024
#define KSL     192
#define NKS2    12        // 32x32x16 K-steps per 192
#define NB      8
#define DIVQ    20
#define TM      32        // rows per tile
#define NT      256       // k_main threads (4 waves)
#define NCH2    256       // chunk width (2 old 128-chunks)
#define MAXTILE (BATCH/TM + NB)   // 1032
#define REG     8192      // per-bucket order region (max bucket ~4500, 60-sigma margin)

#define PBINBLK 64
#define PRPB    (BATCH / PBINBLK)   // 512 rows per binning block
#define PGRID   512                  // 64 bin + 448 conversion blocks

// workspace layout (bytes)
#define WS_WACC16   0
#define WS_W116     (WS_WACC16 + ACCH*KSL*2)        // 393216
#define WS_ORDER    (WS_W116 + 256*2048*2)          // 1441792 (NB*REG ints = 256KB)
#define WS_CNT      (WS_ORDER + NB*REG*4)           // 1703936 (8 ints)

// k_main dynamic LDS: Xb dbuf 2*32*256*2 = 32768
#define LDS_BYTES   32768

// ---------------- dispatch 1: binning+scatter (atomic region reserve) + weight conv ----------------
__global__ __launch_bounds__(512) void k_prep(const float* __restrict__ stm,
                                              const float* __restrict__ Wacc,
                                              const float* __restrict__ W1,
                                              int* __restrict__ cnt,
                                              int* __restrict__ order,
                                              f16* __restrict__ waccF,
                                              f16* __restrict__ w1F)
{
    int tid = threadIdx.x, bid = blockIdx.x;
    if (bid < PBINBLK) {
        __shared__ int bkt_l[PRPB];
        __shared__ int hist[NB], gb[NB];
        if (tid < NB) hist[tid] = 0;
        __syncthreads();
        int wv = tid >> 6, ln = tid & 63;
        int rb = wv * (PRPB / 8);               // 64 rows per wave (local)
        int rowbase = bid * PRPB;
        for (int i = 0; i < PRPB / 8; i++) {
            int lrow = rb + i;
            const float* rp = stm + (long)(rowbase + lrow) * NF;
            float s2 = 0.f;
            for (int k = ln; k < NF; k += 64) s2 += rp[k];
            for (int off = 32; off > 0; off >>= 1) s2 += __shfl_down(s2, off);
            if (ln == 0) {
                int pc = (int)(s2 + 0.5f);
                int b = pc / DIVQ; if (b > NB - 1) b = NB - 1;
                bkt_l[lrow] = b;
                atomicAdd(&hist[b], 1);
            }
        }
        __syncthreads();
        if (tid < NB) gb[tid] = atomicAdd(&cnt[tid], hist[tid]);   // one global atomic per (block,bucket)
        __syncthreads();
        if (tid < NB) hist[tid] = gb[tid];      // reuse hist as local cursor
        __syncthreads();
        for (int i = tid; i < PRPB; i += 512) {
            int b = bkt_l[i];
            int pos = atomicAdd(&hist[b], 1);   // LDS cursor
            if (pos < REG) order[b * REG + pos] = rowbase + i;
        }
    } else {
        int t0 = (bid - PBINBLK) * 512 + tid;
        const int STRIDE = (PGRID - PBINBLK) * 512;   // 229376
        // waccF (32x32x16 B-frag): idx = (((c*12+ks)*2+kh)*128+n)*8+e, k=ks*16+kh*8+e
        for (int t = t0; t < ACCH * KSL; t += STRIDE) {
            int e = t & 7, f = t >> 3;
            int n = f & 127, g = f >> 7;
            int kh = g & 1, h = g >> 1;
            int ks = h % NKS2, c = h / NKS2;
            int k = ks * 16 + kh * 8 + e;
            waccF[t] = (f16)((k < NF) ? Wacc[(c * 128 + n) * NF + k] : 0.f);
        }
        // w1F (16x16x32 B-frag): output-linear
        for (int f = t0; f < 256 * 2048 / 8; f += STRIDE) {
            int n = f & 31, g = f >> 5;
            int l4b = g & 3, ks = (g >> 2) & 3, c = (g >> 4) & 7;
            int s = (g >> 7) & 1, bkt = g >> 8;
            int k0 = s * 1024 + c * 128 + ks * 32 + l4b * 8;
            const float* src = W1 + (long)(bkt * 32 + n) * 2048 + k0;
            float4 va = *(const float4*)(src);
            float4 vb = *(const float4*)(src + 4);
            f16x8 h;
            h[0]=(f16)va.x; h[1]=(f16)va.y; h[2]=(f16)va.z; h[3]=(f16)va.w;
            h[4]=(f16)vb.x; h[5]=(f16)vb.y; h[6]=(f16)vb.z; h[7]=(f16)vb.w;
            *(f16x8*)(w1F + (long)f * 8) = h;
        }
    }
}

// ---------------- dispatch 2: main fused NNUE ----------------
// VGPR cap law: cap = 2048/(8*arg); arg=2 -> 128. Body demand ~110 -> no spill.
__global__ __launch_bounds__(NT, 2) void k_main(
    const float* __restrict__ stm, const float* __restrict__ nstm,
    const float* __restrict__ Wacc, const float* __restrict__ bacc,
    const float* __restrict__ b1, const float* __restrict__ W2,
    const float* __restrict__ b2, const float* __restrict__ W3,
    const float* __restrict__ b3,
    const f16* __restrict__ waccF, const f16* __restrict__ w1F,
    const int* __restrict__ cnt, const int* __restrict__ order,
    float* __restrict__ out)
{
    // ---- inline tile map from the 8 counters ----
    int t = blockIdx.x;
    int bkt = -1, tile = 0, cb = 0, acc0i = 0;
    #pragma unroll
    for (int b = 0; b < NB; b++) {
        int cbv = cnt[b];
        int nb = (cbv + TM - 1) / TM;
        if (bkt < 0 && t < acc0i + nb) { bkt = b; tile = t - acc0i; cb = cbv; }
        acc0i += nb;
    }
    if (bkt < 0) return;
    int rowbase = bkt * REG + tile * TM;        // index into order regions
    int nrows = cb - tile * TM; if (nrows > TM) nrows = TM;

    extern __shared__ __align__(16) char lds_raw[];
    f16* Xb  = (f16*)lds_raw;                   // [2][32][256] dbuf swizzled
    f16* h1s = (f16*)lds_raw;                   // [32][40] alias buf0
    f16* h2s = (f16*)(lds_raw + TM * 40 * 2);   // [32][40] alias buf0

    int tid = threadIdx.x;
    int wv = tid >> 6, ln = tid & 63;
    int l15 = ln & 15, l4 = ln >> 4, l31 = ln & 31, kh = ln >> 5;
    int mt = wv >> 1, nh = wv & 1;
    int colc = wv * 32 + l31;                   // col within old-128-chunk (0..127)

    int rowclamp = (l31 < nrows) ? l31 : (nrows - 1);
    int rowidx = order[rowbase + rowclamp];

    float bb1 = b1[bkt * 32 + nh * 16 + l15];
    f32x4 h1a; h1a[0] = h1a[1] = h1a[2] = h1a[3] = bb1;
    f32x4 h1b; h1b[0] = h1b[1] = h1b[2] = h1b[3] = 0.f;

    const float* psqw = Wacc + (long)ACCH * NF;
    const f16x8* wfr  = (const f16x8*)waccF;
    const f16x8* w1fr = (const f16x8*)w1F;
    float psqr = 0.f;                           // psqt lives in wave-0 registers

    for (int s = 0; s < 2; s++) {
        const float* rp = (s ? nstm : stm) + (long)rowidx * NF;
        // ---- A-panel (12 x f16x8) direct from global; psqt FMAs on wave 0 ----
        f16x8 af[NKS2];
        float pp = 0.f;
        #pragma unroll
        for (int ks = 0; ks < NKS2; ks++) {
            int k0 = ks * 16 + kh * 8;
            float v0=0.f,v1=0.f,v2=0.f,v3=0.f,v4=0.f,v5=0.f,v6=0.f,v7=0.f;
            if (k0 <= 152) {
                float2 a0 = *(const float2*)(rp + k0);
                float2 a1 = *(const float2*)(rp + k0 + 2);
                float2 a2 = *(const float2*)(rp + k0 + 4);
                float2 a3 = *(const float2*)(rp + k0 + 6);
                v0=a0.x; v1=a0.y; v2=a1.x; v3=a1.y;
                v4=a2.x; v5=a2.y; v6=a3.x; v7=a3.y;
                if (wv == 0) {
                    float4 pa = *(const float4*)(psqw + k0);
                    float4 pb = *(const float4*)(psqw + k0 + 4);
                    pp += v0*pa.x + v1*pa.y + v2*pa.z + v3*pa.w
                        + v4*pb.x + v5*pb.y + v6*pb.z + v7*pb.w;
                }
            } else if (k0 == 160) {
                float2 a0 = *(const float2*)(rp + 160);
                v0 = a0.x; v1 = a0.y;
                if (wv == 0) pp += v0*psqw[160] + v1*psqw[161];
            }
            f16x8 h;
            h[0]=(f16)v0; h[1]=(f16)v1; h[2]=(f16)v2; h[3]=(f16)v3;
            h[4]=(f16)v4; h[5]=(f16)v5; h[6]=(f16)v6; h[7]=(f16)v7;
            af[ks] = h;
        }
        if (wv == 0) {
            pp += __shfl_xor(pp, 32);           // combine kh halves
            psqr += s ? (-0.5f * pp) : (0.5f * pp);
        }

        for (int C = 0; C < 4; C++) {           // 4 chunks of 256
            int oc0 = 2 * C, oc1 = 2 * C + 1;
            float bias0 = bacc[oc0 * 128 + colc];
            float bias1 = bacc[oc1 * 128 + colc];
            f32x16 a0, a1;
            #pragma unroll
            for (int q = 0; q < 16; q++) { a0[q] = bias0; a1[q] = bias1; }
            const f16x8* wp0 = wfr + ((oc0 * NKS2) * 2 + kh) * 128 + colc;
            const f16x8* wp1 = wfr + ((oc1 * NKS2) * 2 + kh) * 128 + colc;
            #pragma unroll
            for (int ks = 0; ks < NKS2; ks++) {   // 2 independent MFMA chains
                f16x8 bf0 = wp0[ks * 256];
                a0 = __builtin_amdgcn_mfma_f32_32x32x16_f16(af[ks], bf0, a0, 0, 0, 0);
                f16x8 bf1 = wp1[ks * 256];
                a1 = __builtin_amdgcn_mfma_f32_32x32x16_f16(af[ks], bf1, a1, 0, 0, 0);
            }
            // epilogue: clip^2 -> Xb[(s*4+C)&1], swizzle slot = (xcol>>3) ^ row
            f16* xb = Xb + (((s << 2) | C) & 1) * TM * NCH2;
            #pragma unroll
            for (int reg = 0; reg < 16; reg++) {
                int rr = 4 * kh + (reg & 3) + 8 * (reg >> 2);
                int xc0 = colc, xc1 = 128 + colc;
                float v = fminf(fmaxf(a0[reg], 0.f), 1.f);
                xb[rr * NCH2 + ((((xc0 >> 3) ^ rr) & 31) << 3) + (xc0 & 7)] = (f16)(v * v);
                float w = fminf(fmaxf(a1[reg], 0.f), 1.f);
                xb[rr * NCH2 + ((((xc1 >> 3) ^ rr) & 31) << 3) + (xc1 & 7)] = (f16)(w * w);
            }
            __syncthreads();   // dbuf: single barrier per 256-chunk
            // ---- phase 2: h1 += act @ W1^T over K=256 (2 alternating chains) ----
            const f16x8* w1p = w1fr + (((bkt * 2 + s) * 8) + 2 * C) * 512;
            int row = mt * 16 + l15;
            #pragma unroll
            for (int ks = 0; ks < 8; ks++) {
                int s0 = ks * 4 + l4;          // 16B slot in [0,32)
                f16x8 a = *(const f16x8*)(xb + row * NCH2 + (((s0 ^ row) & 31) << 3));
                f16x8 b = w1p[ks * 128 + l4 * 32 + nh * 16 + l15];
                if (ks & 1) h1b = __builtin_amdgcn_mfma_f32_16x16x32_f16(a, b, h1b, 0, 0, 0);
                else        h1a = __builtin_amdgcn_mfma_f32_16x16x32_f16(a, b, h1a, 0, 0, 0);
            }
        }
    }
    __syncthreads();   // all phase2 reads done before h1s/h2s overwrite buf0

    // ---- h1 finalize: merge chains, clip ----
    #pragma unroll
    for (int jr = 0; jr < 4; jr++) {
        int row = mt * 16 + l4 * 4 + jr;
        int col = nh * 16 + l15;
        float v = fminf(fmaxf(h1a[jr] + h1b[jr], 0.f), 1.f);
        h1s[row * 40 + col] = (f16)v;
    }
    __syncthreads();

    // ---- layer 3 ----
    {
        int nn = nh * 16 + l15;
        const float* w2r = W2 + (bkt * 32 + nn) * 32;
        float4 wa = *(const float4*)(w2r + l4 * 8);
        float4 wb = *(const float4*)(w2r + l4 * 8 + 4);
        f16x8 bfr;
        bfr[0]=(f16)wa.x; bfr[1]=(f16)wa.y; bfr[2]=(f16)wa.z; bfr[3]=(f16)wa.w;
        bfr[4]=(f16)wb.x; bfr[5]=(f16)wb.y; bfr[6]=(f16)wb.z; bfr[7]=(f16)wb.w;
        int row = mt * 16 + l15;
        f16x8 a = *(const f16x8*)(h1s + row * 40 + l4 * 8);
        float bb2 = b2[bkt * 32 + nn];
        f32x4 acc2; acc2[0] = acc2[1] = acc2[2] = acc2[3] = bb2;
        acc2 = __builtin_amdgcn_mfma_f32_16x16x32_f16(a, bfr, acc2, 0, 0, 0);
        #pragma unroll
        for (int jr = 0; jr < 4; jr++) {
            int r2 = mt * 16 + l4 * 4 + jr;
            float v = fminf(fmaxf(acc2[jr], 0.f), 1.f);
            h2s[r2 * 40 + nn] = (f16)v;
        }
    }
    __syncthreads();

    // ---- layer 4 + psqt (wave 0: lane tid == row tid) ----
    if (tid < nrows) {
        const float* w3r = W3 + bkt * 32;
        float o = b3[bkt] + psqr;
        #pragma unroll 8
        for (int n = 0; n < 32; n++) o += (float)h2s[tid * 40 + n] * w3r[n];
        out[rowidx] = o;
    }
}

// ---------------- launcher ----------------
extern "C" void kernel_launch(void* const* d_in, const int* in_sizes, int n_in,
                              void* d_out, int out_size, void* d_ws, size_t ws_size,
                              hipStream_t stream)
{
    (void)in_sizes; (void)n_in; (void)out_size; (void)ws_size;
    const float* stm  = (const float*)d_in[0];
    const float* nstm = (const float*)d_in[1];
    const float* Wacc = (const float*)d_in[2];
    const float* bacc = (const float*)d_in[3];
    const float* W1   = (const float*)d_in[4];
    const float* b1   = (const float*)d_in[5];
    const float* W2   = (const float*)d_in[6];
    const float* b2   = (const float*)d_in[7];
    const float* W3   = (const float*)d_in[8];
    const float* b3   = (const float*)d_in[9];
    float* out = (float*)d_out;

    char* ws = (char*)d_ws;
    f16* waccF  = (f16*)(ws + WS_WACC16);
    f16* w1F    = (f16*)(ws + WS_W116);
    int* order  = (int*)(ws + WS_ORDER);
    int* cnt    = (int*)(ws + WS_CNT);

    hipMemsetAsync(cnt, 0, NB * sizeof(int), stream);
    hipLaunchKernelGGL(k_prep, dim3(PGRID), dim3(512), 0, stream,
                       stm, Wacc, W1, cnt, order, waccF, w1F);

    hipFuncSetAttribute(reinterpret_cast<const void*>(k_main),
                        hipFuncAttributeMaxDynamicSharedMemorySize, LDS_BYTES);
    hipLaunchKernelGGL(k_main, dim3(MAXTILE), dim3(NT), LDS_BYTES, stream,
                       stm, nstm, Wacc, bacc, b1, W2, b2, W3, b3,
                       waccF, w1F, cnt, order, out);
}

// Round 12
// 172.082 us; speedup vs baseline: 1.6104x; 1.6104x over previous
//
#include <hip/hip_runtime.h>

typedef _Float16 f16;
typedef f16 f16x8 __attribute__((ext_vector_type(8)));
typedef float f32x4 __attribute__((ext_vector_type(4)));
typedef float f32x16 __attribute__((ext_vector_type(16)));

#define BATCH   32768
#define NF      162
#define ACCH    1024
#define KSL     192
#define NKS2    12        // 32x32x16 K-steps per 192
#define NB      8
#define DIVQ    20
#define TM      32        // rows per tile
#define NT      256       // k_main threads (4 waves)
#define NCH     128       // chunk width (R10 proven)
#define NCHUNK  (ACCH/NCH) // 8
#define MAXTILE (BATCH/TM + NB)   // 1032
#define REG     8192      // per-bucket order region (max bucket ~4500)

#define PBIN    128       // binning blocks (256 rows each, thread-per-row)
#define PROWS   256
#define PGRID   512       // 128 bin + 384 conversion blocks

// workspace layout (bytes)
#define WS_WACC16   0
#define WS_W116     (WS_WACC16 + ACCH*KSL*2)        // 393216
#define WS_ORDER    (WS_W116 + 256*2048*2)          // 1441792 (NB*REG ints)
#define WS_CNT      (WS_ORDER + NB*REG*4)           // (8 ints)

// k_main dynamic LDS: Xb dbuf 2*32*128*2 = 16384
#define LDS_BYTES   16384

// ---------------- dispatch 1: thread-per-row binning + region scatter + weight conv ----------------
__global__ __launch_bounds__(256) void k_prep(const float* __restrict__ stm,
                                              const float* __restrict__ Wacc,
                                              const float* __restrict__ W1,
                                              int* __restrict__ cnt,
                                              int* __restrict__ order,
                                              f16* __restrict__ waccF,
                                              f16* __restrict__ w1F)
{
    int tid = threadIdx.x, bid = blockIdx.x;
    if (bid < PBIN) {
        __shared__ int bkt_l[PROWS];
        __shared__ int hist[NB], gb[NB];
        if (tid < NB) hist[tid] = 0;
        __syncthreads();
        int row = bid * PROWS + tid;             // thread-per-row, fully parallel
        const float* rp = stm + (long)row * NF;
        float s = 0.f;
        #pragma unroll 8
        for (int q = 0; q < 40; q++) {
            float4 v = *(const float4*)(rp + q * 4);
            s += (v.x + v.y) + (v.z + v.w);
        }
        { float2 v = *(const float2*)(rp + 160); s += v.x + v.y; }
        int pc = (int)(s + 0.5f);
        int b = pc / DIVQ; if (b > NB - 1) b = NB - 1;
        bkt_l[tid] = b;
        atomicAdd(&hist[b], 1);                  // LDS atomic
        __syncthreads();
        if (tid < NB) gb[tid] = atomicAdd(&cnt[tid], hist[tid]);  // 1 global atomic/(blk,bkt)
        __syncthreads();
        if (tid < NB) hist[tid] = gb[tid];       // reuse as cursor
        __syncthreads();
        int b2 = bkt_l[tid];
        int pos = atomicAdd(&hist[b2], 1);       // LDS cursor
        if (pos < REG) order[b2 * REG + pos] = row;
    } else {
        int t0 = (bid - PBIN) * 256 + tid;
        const int STRIDE = (PGRID - PBIN) * 256;   // 98304
        // waccF (32x32x16 B-frag): idx = (((c*12+ks)*2+kh)*128+n)*8+e, k=ks*16+kh*8+e
        for (int t = t0; t < ACCH * KSL; t += STRIDE) {
            int e = t & 7, f = t >> 3;
            int n = f & 127, g = f >> 7;
            int kh = g & 1, h = g >> 1;
            int ks = h % NKS2, c = h / NKS2;
            int k = ks * 16 + kh * 8 + e;
            waccF[t] = (f16)((k < NF) ? Wacc[(c * 128 + n) * NF + k] : 0.f);
        }
        // w1F (16x16x32 B-frag): output-linear, one thread per f16x8
        for (int f = t0; f < 256 * 2048 / 8; f += STRIDE) {
            int n = f & 31, g = f >> 5;
            int l4b = g & 3, ks = (g >> 2) & 3, c = (g >> 4) & 7;
            int s = (g >> 7) & 1, bkt = g >> 8;
            int k0 = s * 1024 + c * 128 + ks * 32 + l4b * 8;
            const float* src = W1 + (long)(bkt * 32 + n) * 2048 + k0;
            float4 va = *(const float4*)(src);
            float4 vb = *(const float4*)(src + 4);
            f16x8 h;
            h[0]=(f16)va.x; h[1]=(f16)va.y; h[2]=(f16)va.z; h[3]=(f16)va.w;
            h[4]=(f16)vb.x; h[5]=(f16)vb.y; h[6]=(f16)vb.z; h[7]=(f16)vb.w;
            *(f16x8*)(w1F + (long)f * 8) = h;
        }
    }
}

// ---------------- dispatch 2: main fused NNUE (R10-proven body) ----------------
// VGPR cap law: cap = 2048/(8*arg); arg=2 -> 128. R10 measured VGPR=80, no spill.
__global__ __launch_bounds__(NT, 2) void k_main(
    const float* __restrict__ stm, const float* __restrict__ nstm,
    const float* __restrict__ Wacc, const float* __restrict__ bacc,
    const float* __restrict__ b1, const float* __restrict__ W2,
    const float* __restrict__ b2, const float* __restrict__ W3,
    const float* __restrict__ b3,
    const f16* __restrict__ waccF, const f16* __restrict__ w1F,
    const int* __restrict__ cnt, const int* __restrict__ order,
    float* __restrict__ out)
{
    // ---- inline tile map from the 8 counters ----
    int t = blockIdx.x;
    int bkt = -1, tile = 0, cb = 0, acc0i = 0;
    #pragma unroll
    for (int b = 0; b < NB; b++) {
        int cbv = cnt[b];
        int nb = (cbv + TM - 1) / TM;
        if (bkt < 0 && t < acc0i + nb) { bkt = b; tile = t - acc0i; cb = cbv; }
        acc0i += nb;
    }
    if (bkt < 0) return;
    int rowbase = bkt * REG + tile * TM;
    int nrows = cb - tile * TM; if (nrows > TM) nrows = TM;

    extern __shared__ __align__(16) char lds_raw[];
    f16* Xb  = (f16*)lds_raw;                           // [2][32][128] dbuf swizzled
    f16* h1s = (f16*)lds_raw;                           // [32][40] alias buf0
    f16* h2s = (f16*)(lds_raw + TM * 40 * 2);           // [32][40] alias buf0

    int tid = threadIdx.x;
    int wv = tid >> 6, ln = tid & 63;
    int l15 = ln & 15, l4 = ln >> 4, l31 = ln & 31, kh = ln >> 5;
    int mt = wv >> 1, nh = wv & 1;
    int colc = wv * 32 + l31;                 // phase1 col within chunk

    int rowclamp = (l31 < nrows) ? l31 : (nrows - 1);
    int rowidx = order[rowbase + rowclamp];

    float bb1 = b1[bkt * 32 + nh * 16 + l15];
    f32x4 h1acc; h1acc[0] = h1acc[1] = h1acc[2] = h1acc[3] = bb1;

    const float* psqw = Wacc + (long)ACCH * NF;
    const f16x8* wfr  = (const f16x8*)waccF;
    const f16x8* w1fr = (const f16x8*)w1F;
    float psqr = 0.f;                          // psqt in wave-0 registers

    for (int s = 0; s < 2; s++) {
        const float* rp = (s ? nstm : stm) + (long)rowidx * NF;
        // ---- A-panel (12 x f16x8 per lane) direct from global; psqt on wave 0 only ----
        f16x8 af[NKS2];
        float pp = 0.f;
        #pragma unroll
        for (int ks = 0; ks < NKS2; ks++) {
            int k0 = ks * 16 + kh * 8;
            float v0=0.f,v1=0.f,v2=0.f,v3=0.f,v4=0.f,v5=0.f,v6=0.f,v7=0.f;
            if (k0 <= 152) {
                float2 a0 = *(const float2*)(rp + k0);
                float2 a1 = *(const float2*)(rp + k0 + 2);
                float2 a2 = *(const float2*)(rp + k0 + 4);
                float2 a3 = *(const float2*)(rp + k0 + 6);
                v0=a0.x; v1=a0.y; v2=a1.x; v3=a1.y;
                v4=a2.x; v5=a2.y; v6=a3.x; v7=a3.y;
                if (wv == 0) {
                    float4 pa = *(const float4*)(psqw + k0);
                    float4 pb = *(const float4*)(psqw + k0 + 4);
                    pp += v0*pa.x + v1*pa.y + v2*pa.z + v3*pa.w
                        + v4*pb.x + v5*pb.y + v6*pb.z + v7*pb.w;
                }
            } else if (k0 == 160) {
                float2 a0 = *(const float2*)(rp + 160);
                v0 = a0.x; v1 = a0.y;
                if (wv == 0) pp += v0*psqw[160] + v1*psqw[161];
            }
            f16x8 h;
            h[0]=(f16)v0; h[1]=(f16)v1; h[2]=(f16)v2; h[3]=(f16)v3;
            h[4]=(f16)v4; h[5]=(f16)v5; h[6]=(f16)v6; h[7]=(f16)v7;
            af[ks] = h;
        }
        if (wv == 0) {
            pp += __shfl_xor(pp, 32);          // combine kh halves
            psqr += s ? (-0.5f * pp) : (0.5f * pp);
        }

        for (int c = 0; c < NCHUNK; c++) {
            // ---- phase 1: 32x32x16, A regs, B global (L2-hot) ----
            float bias = bacc[c * NCH + colc];
            f32x16 acc;
            #pragma unroll
            for (int q = 0; q < 16; q++) acc[q] = bias;
            const f16x8* wp = wfr + ((c * NKS2) * 2 + kh) * 128 + colc;
            #pragma unroll
            for (int ks = 0; ks < NKS2; ks++) {
                f16x8 bf = wp[ks * 256];
                acc = __builtin_amdgcn_mfma_f32_32x32x16_f16(af[ks], bf, acc, 0, 0, 0);
            }
            // epilogue: clip^2 -> Xb[(s*8+c)&1] (dbuf: 1 barrier per chunk)
            f16* xb = Xb + (((s << 3) | c) & 1) * TM * NCH;
            #pragma unroll
            for (int reg = 0; reg < 16; reg++) {
                int rr = 4 * kh + (reg & 3) + 8 * (reg >> 2);
                float v = acc[reg];
                v = fminf(fmaxf(v, 0.f), 1.f);
                v = v * v;
                xb[rr * NCH + ((((colc >> 3) ^ (rr & 7)) << 3) | (colc & 7))] = (f16)v;
            }
            __syncthreads();
            // ---- phase 2: h1 += act @ W1_chunk^T (16x16x32) ----
            const f16x8* w1p = w1fr + ((bkt * 2 + s) * 8 + c) * 512;
            #pragma unroll
            for (int ks = 0; ks < NCH / 32; ks++) {
                int s0 = ks * 4 + l4;
                int row = mt * 16 + l15;
                f16x8 a = *(const f16x8*)(xb + row * NCH + ((s0 ^ (row & 7)) << 3));
                f16x8 b = w1p[s0 * 32 + nh * 16 + l15];
                h1acc = __builtin_amdgcn_mfma_f32_16x16x32_f16(a, b, h1acc, 0, 0, 0);
            }
        }
    }
    __syncthreads();   // all phase2 reads done before h1s/h2s overwrite buf0

    // ---- h1 finalize ----
    #pragma unroll
    for (int jr = 0; jr < 4; jr++) {
        int row = mt * 16 + l4 * 4 + jr;
        int col = nh * 16 + l15;
        float v = fminf(fmaxf(h1acc[jr], 0.f), 1.f);
        h1s[row * 40 + col] = (f16)v;
    }
    __syncthreads();

    // ---- layer 3 ----
    {
        int nn = nh * 16 + l15;
        const float* w2r = W2 + (bkt * 32 + nn) * 32;
        float4 wa = *(const float4*)(w2r + l4 * 8);
        float4 wb = *(const float4*)(w2r + l4 * 8 + 4);
        f16x8 bfr;
        bfr[0]=(f16)wa.x; bfr[1]=(f16)wa.y; bfr[2]=(f16)wa.z; bfr[3]=(f16)wa.w;
        bfr[4]=(f16)wb.x; bfr[5]=(f16)wb.y; bfr[6]=(f16)wb.z; bfr[7]=(f16)wb.w;
        int row = mt * 16 + l15;
        f16x8 a = *(const f16x8*)(h1s + row * 40 + l4 * 8);
        float bb2 = b2[bkt * 32 + nn];
        f32x4 acc2; acc2[0] = acc2[1] = acc2[2] = acc2[3] = bb2;
        acc2 = __builtin_amdgcn_mfma_f32_16x16x32_f16(a, bfr, acc2, 0, 0, 0);
        #pragma unroll
        for (int jr = 0; jr < 4; jr++) {
            int r2 = mt * 16 + l4 * 4 + jr;
            float v = fminf(fmaxf(acc2[jr], 0.f), 1.f);
            h2s[r2 * 40 + nn] = (f16)v;
        }
    }
    __syncthreads();

    // ---- layer 4 + psqt (wave 0: lane tid == row tid, psqr held per-lane) ----
    if (tid < nrows) {
        const float* w3r = W3 + bkt * 32;
        float o = b3[bkt] + psqr;
        #pragma unroll 8
        for (int n = 0; n < 32; n++) o += (float)h2s[tid * 40 + n] * w3r[n];
        out[rowidx] = o;
    }
}

// ---------------- launcher ----------------
extern "C" void kernel_launch(void* const* d_in, const int* in_sizes, int n_in,
                              void* d_out, int out_size, void* d_ws, size_t ws_size,
                              hipStream_t stream)
{
    (void)in_sizes; (void)n_in; (void)out_size; (void)ws_size;
    const float* stm  = (const float*)d_in[0];
    const float* nstm = (const float*)d_in[1];
    const float* Wacc = (const float*)d_in[2];
    const float* bacc = (const float*)d_in[3];
    const float* W1   = (const float*)d_in[4];
    const float* b1   = (const float*)d_in[5];
    const float* W2   = (const float*)d_in[6];
    const float* b2   = (const float*)d_in[7];
    const float* W3   = (const float*)d_in[8];
    const float* b3   = (const float*)d_in[9];
    float* out = (float*)d_out;

    char* ws = (char*)d_ws;
    f16* waccF  = (f16*)(ws + WS_WACC16);
    f16* w1F    = (f16*)(ws + WS_W116);
    int* order  = (int*)(ws + WS_ORDER);
    int* cnt    = (int*)(ws + WS_CNT);

    hipMemsetAsync(cnt, 0, NB * sizeof(int), stream);
    hipLaunchKernelGGL(k_prep, dim3(PGRID), dim3(256), 0, stream,
                       stm, Wacc, W1, cnt, order, waccF, w1F);

    hipFuncSetAttribute(reinterpret_cast<const void*>(k_main),
                        hipFuncAttributeMaxDynamicSharedMemorySize, LDS_BYTES);
    hipLaunchKernelGGL(k_main, dim3(MAXTILE), dim3(NT), LDS_BYTES, stream,
                       stm, nstm, Wacc, bacc, b1, W2, b2, W3, b3,
                       waccF, w1F, cnt, order, out);
}